// Round 1
// baseline (698.714 us; speedup 1.0000x reference)
//
#include <hip/hip_runtime.h>
#include <hip/hip_bf16.h>
#include <stdint.h>

// bf16 MFMA fragment types (per cdna_hip_programming.md §3, compile-verified form)
typedef __attribute__((ext_vector_type(8))) short bf16x8;
typedef __attribute__((ext_vector_type(4))) float f32x4;

// fp32 -> bf16 with round-to-nearest-even (bit trick; NaN irrelevant here)
__device__ __forceinline__ short f2bf(float f) {
    union { float f; uint32_t u; } v; v.f = f;
    uint32_t u = v.u;
    u += 0x7fffu + ((u >> 16) & 1u);
    return (short)(u >> 16);
}

// out[row] = sigmoid(x[row,:] @ Wi + b + state@stateW) @ ow + ob
// One wave processes 64 rows per chunk iteration (4 m-tiles of 16 rows,
// mfma_f32_16x16x32_bf16, N=64 as 4 n-tiles, K=64 as 2 k-steps).
__global__ __launch_bounds__(256) void jordon_kernel(
    const float* __restrict__ x,      // B x 64
    const float* __restrict__ Wi,     // 64 x 64 (D x U, row-major)
    const float* __restrict__ state,  // L
    const float* __restrict__ stateW, // L x 1 x 64
    const float* __restrict__ bias,   // 64
    const float* __restrict__ ow,     // 64
    const float* __restrict__ ob,     // 1
    float* __restrict__ out,          // B
    long long B, int L)
{
    const int lane = threadIdx.x & 63;
    const int wave = threadIdx.x >> 6;
    const int q = lane >> 4;   // quad 0..3
    const int c = lane & 15;   // 0..15

    // Per-lane epilogue constants: for n-tile t this lane owns col = t*16 + c.
    float bb4[4], ow4[4];
#pragma unroll
    for (int t = 0; t < 4; ++t) {
        const int col = t * 16 + c;
        float s = bias[col];
        for (int l = 0; l < L; ++l) s += state[l] * stateW[l * 64 + col];
        bb4[t] = s;
        ow4[t] = ow[col];
    }
    const float outb = ob[0];

    // Preload W fragments (B-operand): wf[t][ks] holds
    // Wi[k = ks*32 + q*8 + j][n = t*16 + c], j = 0..7.  32 VGPRs total.
    bf16x8 wf[4][2];
#pragma unroll
    for (int t = 0; t < 4; ++t) {
#pragma unroll
        for (int s = 0; s < 2; ++s) {
#pragma unroll
            for (int j = 0; j < 8; ++j) {
                wf[t][s][j] = f2bf(Wi[(s * 32 + q * 8 + j) * 64 + t * 16 + c]);
            }
        }
    }

    const long long chunkCount = (B + 255) / 256;
    for (long long chunk = blockIdx.x; chunk < chunkCount; chunk += gridDim.x) {
        const long long blockRow = chunk * 256 + (long long)wave * 64;
        if (blockRow >= B) continue;

        // Load x for 4 m-tiles of 16 rows. Lane reads 8 consecutive floats at
        // each of 2 k-steps -> 4 float4 loads per tile (16 B/lane, coalesced
        // within rows).
        float4 xr[4][4];
#pragma unroll
        for (int mt = 0; mt < 4; ++mt) {
            const float* xp = x + (blockRow + mt * 16 + c) * 64 + q * 8;
            xr[mt][0] = *(const float4*)(xp + 0);
            xr[mt][1] = *(const float4*)(xp + 4);
            xr[mt][2] = *(const float4*)(xp + 32);
            xr[mt][3] = *(const float4*)(xp + 36);
        }

#pragma unroll
        for (int mt = 0; mt < 4; ++mt) {
            bf16x8 a0, a1;  // A-frag: A[m=lane&15][k=q*8+j] per k-step
            a0[0] = f2bf(xr[mt][0].x); a0[1] = f2bf(xr[mt][0].y);
            a0[2] = f2bf(xr[mt][0].z); a0[3] = f2bf(xr[mt][0].w);
            a0[4] = f2bf(xr[mt][1].x); a0[5] = f2bf(xr[mt][1].y);
            a0[6] = f2bf(xr[mt][1].z); a0[7] = f2bf(xr[mt][1].w);
            a1[0] = f2bf(xr[mt][2].x); a1[1] = f2bf(xr[mt][2].y);
            a1[2] = f2bf(xr[mt][2].z); a1[3] = f2bf(xr[mt][2].w);
            a1[4] = f2bf(xr[mt][3].x); a1[5] = f2bf(xr[mt][3].y);
            a1[6] = f2bf(xr[mt][3].z); a1[7] = f2bf(xr[mt][3].w);

            float partial[4] = {0.f, 0.f, 0.f, 0.f};  // j -> row q*4+j
#pragma unroll
            for (int t = 0; t < 4; ++t) {
                f32x4 acc = {0.f, 0.f, 0.f, 0.f};
                acc = __builtin_amdgcn_mfma_f32_16x16x32_bf16(a0, wf[t][0], acc, 0, 0, 0);
                acc = __builtin_amdgcn_mfma_f32_16x16x32_bf16(a1, wf[t][1], acc, 0, 0, 0);
                // C/D layout: col = t*16 + (lane&15), row = q*4 + j
#pragma unroll
                for (int j = 0; j < 4; ++j) {
                    const float pre = acc[j] + bb4[t];
                    const float h = __builtin_amdgcn_rcpf(1.0f + __expf(-pre));
                    partial[j] = fmaf(h, ow4[t], partial[j]);
                }
            }
            // Reduce over the 16 lanes sharing q (masks 1,2,4,8 stay in-group).
#pragma unroll
            for (int j = 0; j < 4; ++j) {
#pragma unroll
                for (int m = 1; m < 16; m <<= 1)
                    partial[j] += __shfl_xor(partial[j], m, 64);
            }
            if (c == 0) {
                float4 o;
                o.x = partial[0] + outb;
                o.y = partial[1] + outb;
                o.z = partial[2] + outb;
                o.w = partial[3] + outb;
                // rows blockRow + mt*16 + q*4 .. +3, 16B-aligned
                *(float4*)(out + blockRow + mt * 16 + q * 4) = o;
            }
        }
    }
}

extern "C" void kernel_launch(void* const* d_in, const int* in_sizes, int n_in,
                              void* d_out, int out_size, void* d_ws, size_t ws_size,
                              hipStream_t stream) {
    const float* x      = (const float*)d_in[0];
    const float* state  = (const float*)d_in[1];
    const float* Wi     = (const float*)d_in[2];
    const float* stateW = (const float*)d_in[3];
    const float* bias   = (const float*)d_in[4];
    const float* ow     = (const float*)d_in[5];
    const float* ob     = (const float*)d_in[6];
    float* out = (float*)d_out;

    const long long B = (long long)in_sizes[0] / 64;
    const int L = in_sizes[1];

    // Fixed grid + chunk-stride loop: amortizes per-block W-fragment gather.
    const long long chunkCount = (B + 255) / 256;
    int grid = (int)(chunkCount < 2048 ? chunkCount : 2048);
    jordon_kernel<<<grid, 256, 0, stream>>>(x, Wi, state, stateW, bias, ow, ob,
                                            out, B, L);
}

// Round 2
// 695.062 us; speedup vs baseline: 1.0053x; 1.0053x over previous
//
#include <hip/hip_runtime.h>
#include <stdint.h>

typedef __attribute__((ext_vector_type(8))) short bf16x8;
typedef __attribute__((ext_vector_type(4))) float f32x4;

union BF8 { bf16x8 v; uint32_t u[4]; };

// Pack two fp32 -> packed bf16x2 (f0 in low half) with round-half-up.
// 2x v_add + 1x v_perm = 1.5 VALU ops per element.
__device__ __forceinline__ uint32_t pack2bf(float f0, float f1) {
    uint32_t u0 = __float_as_uint(f0) + 0x8000u;
    uint32_t u1 = __float_as_uint(f1) + 0x8000u;
    // v_perm_b32: src0 supplies bytes 4-7, src1 bytes 0-3 of the 64b pool.
    return __builtin_amdgcn_perm(u1, u0, 0x07060302u);
}

__device__ __forceinline__ float fast_exp2(float xv) {
#if __has_builtin(__builtin_amdgcn_exp2f)
    return __builtin_amdgcn_exp2f(xv);
#else
    return exp2f(xv);
#endif
}

#define NLOG2E (-1.44269504088896340736f)

// out[r] = sigmoid(x[r,:] @ Wi + b + state@stateW) @ ow + ob
// Transposed MFMA: D = W^T (A) x x^T (B): C/D rows = units, cols = x-rows.
// One wave does 64 rows per chunk iter (4 row-groups of 16).
__global__ __launch_bounds__(256) void jordon_kernel(
    const float* __restrict__ x,      // B x 64
    const float* __restrict__ Wi,     // 64 x 64 (D x U row-major)
    const float* __restrict__ state,  // L
    const float* __restrict__ stateW, // L x 1 x 64
    const float* __restrict__ bias,   // 64
    const float* __restrict__ ow,     // 64
    const float* __restrict__ ob,     // 1
    float* __restrict__ out,          // B
    long long B, int L)
{
    const int lane = threadIdx.x & 63;
    const int wave = threadIdx.x >> 6;
    const int q = lane >> 4;   // quad 0..3
    const int c = lane & 15;   // 0..15

    // A-operand fragments of -log2e * W^T, preloaded once.
    // wf[ut][ks] holds A[m = ut*16 + c][k = ks*32 + q*8 + i] = s*Wi[k][m], i=0..7
    BF8 wf[4][2];
#pragma unroll
    for (int ut = 0; ut < 4; ++ut) {
#pragma unroll
        for (int ks = 0; ks < 2; ++ks) {
#pragma unroll
            for (int jj = 0; jj < 4; ++jj) {
                const int k0 = ks * 32 + q * 8 + jj * 2;
                const int m = ut * 16 + c;
                wf[ut][ks].u[jj] = pack2bf(NLOG2E * Wi[k0 * 64 + m],
                                           NLOG2E * Wi[(k0 + 1) * 64 + m]);
            }
        }
    }

    // Per-lane epilogue constants: lane (q,c) owns units u = ut*16 + q*4 + j.
    // bb = -log2e * (bias + state . stateW)  (folded into MFMA C-init)
    f32x4 bb[4];
    float owv[4][4];
#pragma unroll
    for (int ut = 0; ut < 4; ++ut) {
#pragma unroll
        for (int j = 0; j < 4; ++j) {
            const int u = ut * 16 + q * 4 + j;
            float s = bias[u];
            for (int l = 0; l < L; ++l) s += state[l] * stateW[l * 64 + u];
            bb[ut][j] = NLOG2E * s;
            owv[ut][j] = ow[u];
        }
    }
    const float outb = ob[0];

    const long long chunkCount = (B + 255) >> 8;
    for (long long chunk = blockIdx.x; chunk < chunkCount; chunk += gridDim.x) {
        const long long rowBase = chunk * 256 + (long long)wave * 64;
        if (rowBase >= B) continue;

        // B-operand fragments: xf[g][ks] holds B[k = ks*32 + q*8 + i][n = c]
        // = x[rowBase + g*16 + c][k].  Loads: 4 float4 per row-group per lane.
        BF8 xf[4][2];
#pragma unroll
        for (int g = 0; g < 4; ++g) {
            const float* xp = x + (rowBase + g * 16 + c) * 64 + q * 8;
            const float4 r0 = *(const float4*)(xp + 0);
            const float4 r1 = *(const float4*)(xp + 4);
            const float4 r2 = *(const float4*)(xp + 32);
            const float4 r3 = *(const float4*)(xp + 36);
            xf[g][0].u[0] = pack2bf(r0.x, r0.y);
            xf[g][0].u[1] = pack2bf(r0.z, r0.w);
            xf[g][0].u[2] = pack2bf(r1.x, r1.y);
            xf[g][0].u[3] = pack2bf(r1.z, r1.w);
            xf[g][1].u[0] = pack2bf(r2.x, r2.y);
            xf[g][1].u[1] = pack2bf(r2.z, r2.w);
            xf[g][1].u[2] = pack2bf(r3.x, r3.y);
            xf[g][1].u[3] = pack2bf(r3.z, r3.w);
        }

#pragma unroll
        for (int g = 0; g < 4; ++g) {
            float s = 0.f;
#pragma unroll
            for (int ut = 0; ut < 4; ++ut) {
                f32x4 acc = bb[ut];  // bias pre-folded, pre-scaled
                acc = __builtin_amdgcn_mfma_f32_16x16x32_bf16(wf[ut][0].v, xf[g][0].v, acc, 0, 0, 0);
                acc = __builtin_amdgcn_mfma_f32_16x16x32_bf16(wf[ut][1].v, xf[g][1].v, acc, 0, 0, 0);
                // D layout: row(unit within tile) = q*4 + j, col(x-row) = c.
                // acc[j] = -log2e * (pre-activation)  ->  h = 1/(1+2^acc)
#pragma unroll
                for (int j = 0; j < 4; ++j) {
                    const float h = __builtin_amdgcn_rcpf(1.0f + fast_exp2(acc[j]));
                    s = fmaf(h, owv[ut][j], s);
                }
            }
            // Units are spread across the 4 quads only: 2-step reduction.
            s += __shfl_xor(s, 16, 64);
            s += __shfl_xor(s, 32, 64);
            if (q == 0) out[rowBase + g * 16 + c] = s + outb;
        }
    }
}

extern "C" void kernel_launch(void* const* d_in, const int* in_sizes, int n_in,
                              void* d_out, int out_size, void* d_ws, size_t ws_size,
                              hipStream_t stream) {
    const float* x      = (const float*)d_in[0];
    const float* state  = (const float*)d_in[1];
    const float* Wi     = (const float*)d_in[2];
    const float* stateW = (const float*)d_in[3];
    const float* bias   = (const float*)d_in[4];
    const float* ow     = (const float*)d_in[5];
    const float* ob     = (const float*)d_in[6];
    float* out = (float*)d_out;

    const long long B = (long long)in_sizes[0] / 64;
    const int L = in_sizes[1];

    const long long chunkCount = (B + 255) >> 8;
    int grid = (int)(chunkCount < 2048 ? chunkCount : 2048);
    jordon_kernel<<<grid, 256, 0, stream>>>(x, Wi, state, stateW, bias, ow, ob,
                                            out, B, L);
}